// Round 7
// baseline (84.335 us; speedup 1.0000x reference)
//
#include <hip/hip_runtime.h>
#include <hip/hip_bf16.h>

typedef __bf16 bf16;
typedef bf16  bf16x2 __attribute__((ext_vector_type(2)));
typedef bf16  bf16x4 __attribute__((ext_vector_type(4)));
typedef bf16  bf16x8 __attribute__((ext_vector_type(8)));
typedef float f32x4  __attribute__((ext_vector_type(4)));
typedef float f32x16 __attribute__((ext_vector_type(16)));

#define MFMA32(A, B, C) __builtin_amdgcn_mfma_f32_32x32x16_bf16((A), (B), (C), 0, 0, 0)

namespace {
constexpr int   kS = 2048, kHq = 16, kHkv = 8, kD = 128, kChunk = 512;
constexpr int   kStrK  = kHkv * kD;                      // floats between keys
constexpr float kLog2e = 1.4426950408889634f;
constexpr float kScale = 0.08838834764831845f * kLog2e;  // exp2-domain softmax
constexpr float kThr   = 8.0f * kLog2e;                  // T13 threshold (log2)
constexpr size_t kWsNeed = 512ull * 8192 * 2 * 2;        // K+V bf16 tiles: 16 MB
}

union U32B { bf16x2 h; unsigned u; };
union PAU  { unsigned u[4]; bf16x8 v; };

// ---------------- prepack: K/V f32 -> bf16 frag-line layout in d_ws ---------
// Tile T = b*256 + n*64 + h*8 + kt holds 8192 bf16 (one 64key x 128d tile).
// K elem (key,d)  -> (((key>>5)*8 + (d>>4))*2 + ((d>>3)&1))*256 + (key&31)*8 + (d&7)
// V elem (key,d)  -> (((d>>5)*4 + (key>>4))*2 + ((key>>3)&1))*256 + (d&31)*8 + (key&7)
// so the main kernel's A-fragments are contiguous 16B/lane coalesced loads.
__global__ __launch_bounds__(256, 4)
void prepack(const float* __restrict__ Kg, const float* __restrict__ Vg,
             bf16* __restrict__ Kws, bf16* __restrict__ Vws) {
  __shared__ __attribute__((aligned(16))) bf16 img[8192];
  const int t  = threadIdx.x;
  const int bk = blockIdx.x;  // = tile index
  const int kt = bk & 7, h = (bk >> 3) & 7, n = (bk >> 6) & 3, b = bk >> 8;
  const size_t rowbase = ((size_t)(b * kS + n * kChunk + kt * 64) * kHkv + h) * kD;

  const float* kp = Kg + rowbase;
#pragma unroll
  for (int it = 0; it < 8; ++it) {
    const int idx = it * 256 + t, key = idx >> 5, d4 = idx & 31;
    f32x4 v = *(const f32x4*)(kp + (size_t)key * kStrK + d4 * 4);
#pragma unroll
    for (int j = 0; j < 4; ++j) {
      const int d = d4 * 4 + j;
      img[(((((key >> 5) * 8 + (d >> 4)) * 2 + ((d >> 3) & 1)) << 8) +
           ((key & 31) << 3) + (d & 7))] = (bf16)v[j];
    }
  }
  __syncthreads();
  {
    bf16* dst = Kws + (size_t)bk * 8192;
#pragma unroll
    for (int i = 0; i < 4; ++i)
      *(bf16x8*)(dst + t * 8 + i * 2048) = *(const bf16x8*)(&img[t * 8 + i * 2048]);
  }
  __syncthreads();

  const float* vp = Vg + rowbase;
#pragma unroll
  for (int it = 0; it < 8; ++it) {
    const int idx = it * 256 + t, key = idx >> 5, d4 = idx & 31;
    f32x4 v = *(const f32x4*)(vp + (size_t)key * kStrK + d4 * 4);
#pragma unroll
    for (int j = 0; j < 4; ++j) {
      const int d = d4 * 4 + j;
      img[(((((d >> 5) * 4 + (key >> 4)) * 2 + ((key >> 3) & 1)) << 8) +
           ((d & 31) << 3) + (key & 7))] = (bf16)v[j];
    }
  }
  __syncthreads();
  {
    bf16* dst = Vws + (size_t)bk * 8192;
#pragma unroll
    for (int i = 0; i < 4; ++i)
      *(bf16x8*)(dst + t * 8 + i * 2048) = *(const bf16x8*)(&img[t * 8 + i * 2048]);
  }
}

// ---------------- main: barrier-free streaming flash attention --------------
// 256 blocks (b,n,hq,p) x 512 thr (8 waves x 32 q-rows). NO LDS, NO barriers.
// S^T = K*Q^T -> lane owns q = lane&31; softmax lane-local (exp2 domain).
// O^T = V^T*P^T -> q stays lane-local. K/V fragments streamed from prepacked
// bf16 frag-lines (1 coalesced b128 per fragment).
__global__ __launch_bounds__(512, 2)
void attn_stream(const float* __restrict__ Qg, const bf16* __restrict__ Kws,
                 const bf16* __restrict__ Vws, float* __restrict__ Og) {
  const int t = threadIdx.x, lane = t & 63, w = t >> 6;
  const int l31 = lane & 31, hi = lane >> 5;

  // XCD grouping: 32 blocks of one (b,n) per XCD (K/V L2-local).
  const int bid = blockIdx.x;
  const int gid = (bid & 7) * 32 + (bid >> 3);
  const int p = gid & 1, hq = (gid >> 1) & 15, n = (gid >> 5) & 3, b = (gid >> 7) & 1;
  const int h = hq >> 1;

  // Per-SIMD balanced strips: waves (w, w+4) need 9 tiles together.
  const int a      = (w < 4) ? (7 - 2 * w) : (2 * w - 8);
  const int need   = a + 1;
  const int strip  = 2 * a + p;
  const int qg     = n * kChunk + strip * 32 + l31;
  const int rowoff = 32 * p + l31;

  // ---- Q fragments: B-operand, col=q=l31, k = dk*16 + 8*hi + j ----
  bf16x8 qf[8];
  {
    const float* qp = Qg + ((size_t)(b * kS + qg) * kHq + hq) * kD;
#pragma unroll
    for (int dk = 0; dk < 8; ++dk) {
      f32x4 x0 = *(const f32x4*)(qp + dk * 16 + 8 * hi);
      f32x4 x1 = *(const f32x4*)(qp + dk * 16 + 8 * hi + 4);
      bf16x8 v;
#pragma unroll
      for (int q = 0; q < 4; ++q) { v[q] = (bf16)(x0[q] * kScale); v[4 + q] = (bf16)(x1[q] * kScale); }
      qf[dk] = v;
    }
  }

  f32x16 o[4];  // O^T accum: d = 32*dt + (r&3)+8*(r>>2)+4*hi, col q = l31
#pragma unroll
  for (int dt = 0; dt < 4; ++dt)
#pragma unroll
    for (int r = 0; r < 16; ++r) o[dt][r] = 0.f;
  float m = -1e30f, l = 0.f;

  const bf16* kt0 = Kws + ((size_t)((b * 4 + n) * 8 + h)) * 8 * 8192;
  const bf16* vt0 = Vws + ((size_t)((b * 4 + n) * 8 + h)) * 8 * 8192;

#pragma unroll 1
  for (int kt = 0; kt < need; ++kt) {
    const bf16* ktile = kt0 + (size_t)kt * 8192;
    const bf16* vtile = vt0 + (size_t)kt * 8192;
    const bool  diag  = (kt + 1 == need);

    // ---- QK^T: S^T[key][q], 16 MFMA, frag-line coalesced loads ----
    f32x16 s[2];
#pragma unroll
    for (int ks = 0; ks < 2; ++ks)
#pragma unroll
      for (int r = 0; r < 16; ++r) s[ks][r] = 0.f;
    __builtin_amdgcn_s_setprio(1);
#pragma unroll
    for (int ks = 0; ks < 2; ++ks) {
#pragma unroll
      for (int dk = 0; dk < 8; ++dk) {
        bf16x8 kfr = *(const bf16x8*)(ktile + ((((ks * 8 + dk) * 2 + hi) * 32 + l31) * 8));
        s[ks] = MFMA32(kfr, qf[dk], s[ks]);
      }
    }
    __builtin_amdgcn_s_setprio(0);

    if (diag) {
#pragma unroll
      for (int ks = 0; ks < 2; ++ks)
#pragma unroll
        for (int r = 0; r < 16; ++r) {
          const int key = ks * 32 + (r & 3) + 8 * (r >> 2) + 4 * hi;
          if (key > rowoff) s[ks][r] = -1e30f;
        }
    }
    // ---- lane-local softmax (q = l31; partner = lane^32) ----
    float mx = -1e30f;
#pragma unroll
    for (int ks = 0; ks < 2; ++ks)
#pragma unroll
      for (int r = 0; r < 16; ++r) mx = fmaxf(mx, s[ks][r]);
    mx = fmaxf(mx, __shfl_xor(mx, 32, 64));
    if (__any(mx > m + kThr)) {  // T13 defer-max
      const float mn = fmaxf(m, mx), c = exp2f(m - mn);
      l *= c;
#pragma unroll
      for (int dt = 0; dt < 4; ++dt)
#pragma unroll
        for (int r = 0; r < 16; ++r) o[dt][r] *= c;
      m = mn;
    }
    unsigned u[2][8];
    float lp = 0.f;
#pragma unroll
    for (int ks = 0; ks < 2; ++ks)
#pragma unroll
      for (int q = 0; q < 8; ++q) {
        const float p0 = exp2f(s[ks][2 * q] - m), p1 = exp2f(s[ks][2 * q + 1] - m);
        lp += p0 + p1;
        U32B uu; uu.h = bf16x2{(bf16)p0, (bf16)p1};
        u[ks][q] = uu.u;
      }
    l += lp;
    // ---- half-exchange: interleaved-4 ownership -> contiguous-8 B-frags ----
    unsigned rc[2][4];
#pragma unroll
    for (int ks = 0; ks < 2; ++ks)
#pragma unroll
      for (int i = 0; i < 4; ++i)
        rc[ks][i] = (unsigned)__shfl_xor((int)u[ks][(i & 1) + 4 * (i >> 1) + (hi ? 0 : 2)], 32, 64);
    bf16x8 pa[4];
#pragma unroll
    for (int ks = 0; ks < 2; ++ks)
#pragma unroll
      for (int kh = 0; kh < 2; ++kh) {
        PAU pu;
        pu.u[0] = hi ? rc[ks][2 * kh]     : u[ks][4 * kh];
        pu.u[1] = hi ? rc[ks][2 * kh + 1] : u[ks][4 * kh + 1];
        pu.u[2] = hi ? u[ks][4 * kh + 2]  : rc[ks][2 * kh];
        pu.u[3] = hi ? u[ks][4 * kh + 3]  : rc[ks][2 * kh + 1];
        pa[ks * 2 + kh] = pu.v;
      }
    // ---- PV: O^T += V^T * P^T, 16 MFMA, frag-line coalesced loads ----
    __builtin_amdgcn_s_setprio(1);
#pragma unroll
    for (int dt = 0; dt < 4; ++dt) {
#pragma unroll
      for (int ksl = 0; ksl < 4; ++ksl) {
        bf16x8 vfr = *(const bf16x8*)(vtile + ((((dt * 4 + ksl) * 2 + hi) * 32 + l31) * 8));
        o[dt] = MFMA32(vfr, pa[ksl], o[dt]);
      }
    }
    __builtin_amdgcn_s_setprio(0);
  }

  // ---- epilogue: combine partner l, divide, store O^T regs ----
  l += __shfl_xor(l, 32, 64);
  const float inv = 1.f / l;
  float* op = Og + ((size_t)(b * kS + qg) * kHq + hq) * kD;
#pragma unroll
  for (int dt = 0; dt < 4; ++dt)
#pragma unroll
    for (int rq = 0; rq < 4; ++rq) {
      f32x4 st;
#pragma unroll
      for (int rr = 0; rr < 4; ++rr) st[rr] = o[dt][4 * rq + rr] * inv;
      *(f32x4*)(op + dt * 32 + 8 * rq + 4 * hi) = st;
    }
}

// ---------------- fallback (R4 structure, LDS-staged) if ws too small -------
__global__ __launch_bounds__(512, 2)
void attn_fb(const float* __restrict__ Qg, const float* __restrict__ Kg,
             const float* __restrict__ Vg, float* __restrict__ Og) {
  __shared__ __attribute__((aligned(16))) bf16 ldsK[2][64 * 128];
  __shared__ __attribute__((aligned(16))) bf16 ldsV[2][128 * 64];

  const int t = threadIdx.x, lane = t & 63, w = t >> 6;
  const int l31 = lane & 31, hi = lane >> 5;
  const int bid = blockIdx.x;
  const int gid = (bid & 7) * 32 + (bid >> 3);
  const int p = gid & 1, hq = (gid >> 1) & 15, n = (gid >> 5) & 3, b = (gid >> 7) & 1;
  const int h = hq >> 1;
  const int a = (w < 4) ? (7 - 2 * w) : (2 * w - 8);
  const int need = a + 1, strip = 2 * a + p;
  const int qg = n * kChunk + strip * 32 + l31;
  const int rowoff = 32 * p + l31;

  bf16x8 qf[8];
  {
    const float* qp = Qg + ((size_t)(b * kS + qg) * kHq + hq) * kD;
#pragma unroll
    for (int dk = 0; dk < 8; ++dk) {
      f32x4 x0 = *(const f32x4*)(qp + dk * 16 + 8 * hi);
      f32x4 x1 = *(const f32x4*)(qp + dk * 16 + 8 * hi + 4);
      bf16x8 v;
#pragma unroll
      for (int q = 0; q < 4; ++q) { v[q] = (bf16)(x0[q] * kScale); v[4 + q] = (bf16)(x1[q] * kScale); }
      qf[dk] = v;
    }
  }
  f32x16 o[4];
#pragma unroll
  for (int dt = 0; dt < 4; ++dt)
#pragma unroll
    for (int r = 0; r < 16; ++r) o[dt][r] = 0.f;
  float m = -1e30f, l = 0.f;

  const float* kpz = Kg + ((size_t)(b * kS + n * kChunk) * kHkv + h) * kD;
  const float* vpz = Vg + ((size_t)(b * kS + n * kChunk) * kHkv + h) * kD;
  const int sKey = t >> 5, sD4 = t & 31;
  const int vKp = t & 31, vD4h = t >> 5;

  f32x4 kf[4], va[2], vb[2];
  auto issue = [&](int kt) {
    const float* kp = kpz + (size_t)kt * 64 * kStrK;
    const float* vp = vpz + (size_t)kt * 64 * kStrK;
#pragma unroll
    for (int it = 0; it < 4; ++it)
      kf[it] = *(const f32x4*)(kp + (size_t)(16 * it + sKey) * kStrK + sD4 * 4);
#pragma unroll
    for (int it = 0; it < 2; ++it) {
      va[it] = *(const f32x4*)(vp + (size_t)(2 * vKp) * kStrK + (16 * it + vD4h) * 4);
      vb[it] = *(const f32x4*)(vp + (size_t)(2 * vKp + 1) * kStrK + (16 * it + vD4h) * 4);
    }
  };
  auto stage = [&](int buf) {
#pragma unroll
    for (int it = 0; it < 4; ++it) {
      const int key = 16 * it + sKey;
      bf16x4 kb;
#pragma unroll
      for (int q = 0; q < 4; ++q) kb[q] = (bf16)kf[it][q];
      *(bf16x4*)&ldsK[buf][key * 128 + ((sD4 * 4) ^ ((key & 7) << 3))] = kb;
    }
#pragma unroll
    for (int it = 0; it < 2; ++it) {
#pragma unroll
      for (int q = 0; q < 4; ++q) {
        const int d = (16 * it + vD4h) * 4 + q;
        U32B uu; uu.h = bf16x2{(bf16)va[it][q], (bf16)vb[it][q]};
        *(unsigned*)&ldsV[buf][d * 64 + ((2 * vKp) ^ ((d & 7) << 3))] = uu.u;
      }
    }
  };
  auto compute = [&](int buf, bool diag) {
    f32x16 s[2];
#pragma unroll
    for (int ks = 0; ks < 2; ++ks)
#pragma unroll
      for (int r = 0; r < 16; ++r) s[ks][r] = 0.f;
#pragma unroll
    for (int ks = 0; ks < 2; ++ks) {
      const int key = ks * 32 + l31, swz = (key & 7) << 3;
      const bf16* kb = &ldsK[buf][key * 128];
#pragma unroll
      for (int dk = 0; dk < 8; ++dk) {
        bf16x8 kfr = *(const bf16x8*)&kb[(dk * 16 + 8 * hi) ^ swz];
        s[ks] = MFMA32(kfr, qf[dk], s[ks]);
      }
    }
    if (diag) {
#pragma unroll
      for (int ks = 0; ks < 2; ++ks)
#pragma unroll
        for (int r = 0; r < 16; ++r) {
          const int key = ks * 32 + (r & 3) + 8 * (r >> 2) + 4 * hi;
          if (key > rowoff) s[ks][r] = -1e30f;
        }
    }
    float mx = -1e30f;
#pragma unroll
    for (int ks = 0; ks < 2; ++ks)
#pragma unroll
      for (int r = 0; r < 16; ++r) mx = fmaxf(mx, s[ks][r]);
    mx = fmaxf(mx, __shfl_xor(mx, 32, 64));
    if (__any(mx > m + kThr)) {
      const float mn = fmaxf(m, mx), c = exp2f(m - mn);
      l *= c;
#pragma unroll
      for (int dt = 0; dt < 4; ++dt)
#pragma unroll
        for (int r = 0; r < 16; ++r) o[dt][r] *= c;
      m = mn;
    }
    unsigned u[2][8];
    float lp = 0.f;
#pragma unroll
    for (int ks = 0; ks < 2; ++ks)
#pragma unroll
      for (int q = 0; q < 8; ++q) {
        const float p0 = exp2f(s[ks][2 * q] - m), p1 = exp2f(s[ks][2 * q + 1] - m);
        lp += p0 + p1;
        U32B uu; uu.h = bf16x2{(bf16)p0, (bf16)p1};
        u[ks][q] = uu.u;
      }
    l += lp;
    unsigned rc[2][4];
#pragma unroll
    for (int ks = 0; ks < 2; ++ks)
#pragma unroll
      for (int i = 0; i < 4; ++i)
        rc[ks][i] = (unsigned)__shfl_xor((int)u[ks][(i & 1) + 4 * (i >> 1) + (hi ? 0 : 2)], 32, 64);
    bf16x8 pa[4];
#pragma unroll
    for (int ks = 0; ks < 2; ++ks)
#pragma unroll
      for (int kh = 0; kh < 2; ++kh) {
        PAU pu;
        pu.u[0] = hi ? rc[ks][2 * kh]     : u[ks][4 * kh];
        pu.u[1] = hi ? rc[ks][2 * kh + 1] : u[ks][4 * kh + 1];
        pu.u[2] = hi ? u[ks][4 * kh + 2]  : rc[ks][2 * kh];
        pu.u[3] = hi ? u[ks][4 * kh + 3]  : rc[ks][2 * kh + 1];
        pa[ks * 2 + kh] = pu.v;
      }
#pragma unroll
    for (int dt = 0; dt < 4; ++dt) {
      const int d = dt * 32 + l31, swz = (d & 7) << 3;
      const bf16* vbp = &ldsV[buf][d * 64];
#pragma unroll
      for (int ksl = 0; ksl < 4; ++ksl) {
        bf16x8 vfr = *(const bf16x8*)&vbp[(ksl * 16 + 8 * hi) ^ swz];
        o[dt] = MFMA32(vfr, pa[ksl], o[dt]);
      }
    }
  };

  issue(0); stage(0); issue(1);
  __syncthreads();
#pragma unroll 1
  for (int kt = 0; kt < 8; ++kt) {
    if (kt + 1 < 8) {
      stage((kt + 1) & 1);
      if (kt + 2 < 8) issue(kt + 2);
    }
    if (kt < need) compute(kt & 1, kt + 1 == need);
    if (kt + 1 < 8) __syncthreads();
  }

  l += __shfl_xor(l, 32, 64);
  const float inv = 1.f / l;
  float* op = Og + ((size_t)(b * kS + qg) * kHq + hq) * kD;
#pragma unroll
  for (int dt = 0; dt < 4; ++dt)
#pragma unroll
    for (int rq = 0; rq < 4; ++rq) {
      f32x4 st;
#pragma unroll
      for (int rr = 0; rr < 4; ++rr) st[rr] = o[dt][4 * rq + rr] * inv;
      *(f32x4*)(op + dt * 32 + 8 * rq + 4 * hi) = st;
    }
}

extern "C" void kernel_launch(void* const* d_in, const int* in_sizes, int n_in,
                              void* d_out, int out_size, void* d_ws, size_t ws_size,
                              hipStream_t stream) {
  (void)in_sizes; (void)n_in; (void)out_size;
  const float* Q = (const float*)d_in[0];
  const float* K = (const float*)d_in[1];
  const float* V = (const float*)d_in[2];
  float* O = (float*)d_out;
  if (ws_size >= kWsNeed) {
    bf16* Kws = (bf16*)d_ws;
    bf16* Vws = Kws + 512ull * 8192;  // 8 MB in
    hipLaunchKernelGGL(prepack, dim3(512), dim3(256), 0, stream, K, V, Kws, Vws);
    hipLaunchKernelGGL(attn_stream, dim3(256), dim3(512), 0, stream, Q, Kws, Vws, O);
  } else {
    hipLaunchKernelGGL(attn_fb, dim3(256), dim3(512), 0, stream, Q, K, V, O);
  }
}

// Round 8
// 40.286 us; speedup vs baseline: 2.0934x; 2.0934x over previous
//
#include <hip/hip_runtime.h>
#include <hip/hip_bf16.h>

typedef __bf16 bf16;
typedef bf16  bf16x2 __attribute__((ext_vector_type(2)));
typedef bf16  bf16x4 __attribute__((ext_vector_type(4)));
typedef bf16  bf16x8 __attribute__((ext_vector_type(8)));
typedef float f32x4  __attribute__((ext_vector_type(4)));
typedef float f32x16 __attribute__((ext_vector_type(16)));

#define MFMA32(A, B, C) __builtin_amdgcn_mfma_f32_32x32x16_bf16((A), (B), (C), 0, 0, 0)

namespace {
constexpr int   kS = 2048, kHq = 16, kHkv = 8, kD = 128, kChunk = 512;
constexpr int   kStrK  = kHkv * kD;                      // floats between keys
constexpr float kLog2e = 1.4426950408889634f;
constexpr float kScale = 0.08838834764831845f * kLog2e;  // exp2-domain softmax
constexpr float kThr   = 8.0f * kLog2e;                  // T13 threshold (log2)
}

union U32B { bf16x2 h; unsigned u; };
union PAU  { unsigned u[4]; bf16x8 v; };

// lgkm-only barrier: LDS drained, VMEM prefetch stays in flight across it.
__device__ __forceinline__ void lgkm_barrier() {
  __builtin_amdgcn_sched_barrier(0);
  asm volatile("s_waitcnt lgkmcnt(0)" ::: "memory");
  __builtin_amdgcn_s_barrier();
  __builtin_amdgcn_sched_barrier(0);
}

// Swapped-QK^T chunked-causal GQA attention with WAVE-GROUP STAGGER.
// 256 blocks (b,n,hq,p) x 512 threads (8 waves x 32 q-rows).
// Group A (w<4) computes tile ph; group B (w>=4) computes tile ph-1 on a
// 3-slot LDS ring -> each SIMD has one wave in MFMA while its partner is in
// softmax: breaks the barrier lockstep that idled the pipes (R4/R6 = 35us).
__global__ __launch_bounds__(512, 2)
void attn_chunk(const float* __restrict__ Qg, const float* __restrict__ Kg,
                const float* __restrict__ Vg, float* __restrict__ Og) {
  __shared__ __attribute__((aligned(16))) bf16 ldsK[3][64 * 128];  // [key][d] ^((key&7)<<3)
  __shared__ __attribute__((aligned(16))) bf16 ldsV[3][128 * 64];  // [d][key] ^((d&7)<<3)

  const int t = threadIdx.x, lane = t & 63, w = t >> 6;
  const int l31 = lane & 31, hi = lane >> 5;

  // XCD grouping: 32 blocks of one (b,n) per XCD (K/V L2-local).
  const int bid = blockIdx.x;
  const int gid = (bid & 7) * 32 + (bid >> 3);
  const int p = gid & 1, hq = (gid >> 1) & 15, n = (gid >> 5) & 3, b = (gid >> 7) & 1;
  const int h = hq >> 1;

  // R4 pairing: SIMD s = waves {s, s+4}, needs {8-2s, 2s+1} (sum 9).
  // Group A = w<4 (tile ph), group B = w>=4 (tile ph-1).
  const bool grpA  = (w < 4);
  const int a      = grpA ? (7 - 2 * w) : (2 * w - 8);
  const int need   = a + 1;
  const int strip  = 2 * a + p;
  const int qg     = n * kChunk + strip * 32 + l31;
  const int rowoff = 32 * p + l31;

  // ---- Q fragments: B-operand, col=q=l31, k = dk*16 + 8*hi + j ----
  bf16x8 qf[8];
  {
    const float* qp = Qg + ((size_t)(b * kS + qg) * kHq + hq) * kD;
#pragma unroll
    for (int dk = 0; dk < 8; ++dk) {
      f32x4 x0 = *(const f32x4*)(qp + dk * 16 + 8 * hi);
      f32x4 x1 = *(const f32x4*)(qp + dk * 16 + 8 * hi + 4);
      bf16x8 v;
#pragma unroll
      for (int q = 0; q < 4; ++q) { v[q] = (bf16)(x0[q] * kScale); v[4 + q] = (bf16)(x1[q] * kScale); }
      qf[dk] = v;
    }
  }

  f32x16 o[4];  // O^T accum: d = 32*dt + (r&3)+8*(r>>2)+4*hi, col q = l31
#pragma unroll
  for (int dt = 0; dt < 4; ++dt)
#pragma unroll
    for (int r = 0; r < 16; ++r) o[dt][r] = 0.f;
  float m = -1e30f, l = 0.f;

  const float* kpz = Kg + ((size_t)(b * kS + n * kChunk) * kHkv + h) * kD;
  const float* vpz = Vg + ((size_t)(b * kS + n * kChunk) * kHkv + h) * kD;

  // staging coords (512 threads / 64-key tile):
  const int sKey = t >> 5, sD4 = t & 31;   // K: key = 16*it + sKey
  const int vKp = t & 31, vD4h = t >> 5;   // V: keys {2vKp,2vKp+1}, d4 = 16*it + vD4h

  f32x4 kf[4], va[2], vb[2];  // 1-phase-ahead prefetch registers
  auto issue = [&](int kt) {
    const float* kp = kpz + (size_t)kt * 64 * kStrK;
    const float* vp = vpz + (size_t)kt * 64 * kStrK;
#pragma unroll
    for (int it = 0; it < 4; ++it)
      kf[it] = *(const f32x4*)(kp + (size_t)(16 * it + sKey) * kStrK + sD4 * 4);
#pragma unroll
    for (int it = 0; it < 2; ++it) {
      va[it] = *(const f32x4*)(vp + (size_t)(2 * vKp) * kStrK + (16 * it + vD4h) * 4);
      vb[it] = *(const f32x4*)(vp + (size_t)(2 * vKp + 1) * kStrK + (16 * it + vD4h) * 4);
    }
  };
  auto stage = [&](int buf) {
#pragma unroll
    for (int it = 0; it < 4; ++it) {
      const int key = 16 * it + sKey;
      bf16x4 kb;
#pragma unroll
      for (int q = 0; q < 4; ++q) kb[q] = (bf16)kf[it][q];
      *(bf16x4*)&ldsK[buf][key * 128 + ((sD4 * 4) ^ ((key & 7) << 3))] = kb;
    }
#pragma unroll
    for (int it = 0; it < 2; ++it) {
#pragma unroll
      for (int q = 0; q < 4; ++q) {
        const int d = (16 * it + vD4h) * 4 + q;
        U32B uu; uu.h = bf16x2{(bf16)va[it][q], (bf16)vb[it][q]};
        *(unsigned*)&ldsV[buf][d * 64 + ((2 * vKp) ^ ((d & 7) << 3))] = uu.u;
      }
    }
  };

  auto compute = [&](int buf, bool diag) {
    // ---- QK^T: S^T[key][q], 16 MFMA ----
    f32x16 s[2];
#pragma unroll
    for (int ks = 0; ks < 2; ++ks)
#pragma unroll
      for (int r = 0; r < 16; ++r) s[ks][r] = 0.f;
    __builtin_amdgcn_s_setprio(1);
#pragma unroll
    for (int ks = 0; ks < 2; ++ks) {
      const int key = ks * 32 + l31, swz = (key & 7) << 3;
      const bf16* kb = &ldsK[buf][key * 128];
#pragma unroll
      for (int dk = 0; dk < 8; ++dk) {
        bf16x8 kfr = *(const bf16x8*)&kb[(dk * 16 + 8 * hi) ^ swz];
        s[ks] = MFMA32(kfr, qf[dk], s[ks]);
      }
    }
    __builtin_amdgcn_s_setprio(0);
    if (diag) {
#pragma unroll
      for (int ks = 0; ks < 2; ++ks)
#pragma unroll
        for (int r = 0; r < 16; ++r) {
          const int key = ks * 32 + (r & 3) + 8 * (r >> 2) + 4 * hi;
          if (key > rowoff) s[ks][r] = -1e30f;
        }
    }
    // ---- lane-local softmax, exp2 domain (q = l31; partner = lane^32) ----
    float mx = -1e30f;
#pragma unroll
    for (int ks = 0; ks < 2; ++ks)
#pragma unroll
      for (int r = 0; r < 16; ++r) mx = fmaxf(mx, s[ks][r]);
    mx = fmaxf(mx, __shfl_xor(mx, 32, 64));
    if (__any(mx > m + kThr)) {  // T13 defer-max
      const float mn = fmaxf(m, mx), c = exp2f(m - mn);
      l *= c;
#pragma unroll
      for (int dt = 0; dt < 4; ++dt)
#pragma unroll
        for (int r = 0; r < 16; ++r) o[dt][r] *= c;
      m = mn;
    }
    unsigned u[2][8];
    float lp = 0.f;
#pragma unroll
    for (int ks = 0; ks < 2; ++ks)
#pragma unroll
      for (int q = 0; q < 8; ++q) {
        const float p0 = exp2f(s[ks][2 * q] - m), p1 = exp2f(s[ks][2 * q + 1] - m);
        lp += p0 + p1;
        U32B uu; uu.h = bf16x2{(bf16)p0, (bf16)p1};
        u[ks][q] = uu.u;
      }
    l += lp;
    // ---- half-exchange: interleaved-4 ownership -> contiguous-8 B-frags ----
    unsigned rc[2][4];
#pragma unroll
    for (int ks = 0; ks < 2; ++ks)
#pragma unroll
      for (int i = 0; i < 4; ++i)
        rc[ks][i] = (unsigned)__shfl_xor((int)u[ks][(i & 1) + 4 * (i >> 1) + (hi ? 0 : 2)], 32, 64);
    bf16x8 pa[4];
#pragma unroll
    for (int ks = 0; ks < 2; ++ks)
#pragma unroll
      for (int kh = 0; kh < 2; ++kh) {
        PAU pu;
        pu.u[0] = hi ? rc[ks][2 * kh]     : u[ks][4 * kh];
        pu.u[1] = hi ? rc[ks][2 * kh + 1] : u[ks][4 * kh + 1];
        pu.u[2] = hi ? u[ks][4 * kh + 2]  : rc[ks][2 * kh];
        pu.u[3] = hi ? u[ks][4 * kh + 3]  : rc[ks][2 * kh + 1];
        pa[ks * 2 + kh] = pu.v;
      }
    // ---- PV: O^T += V^T * P^T, 16 MFMA ----
    __builtin_amdgcn_s_setprio(1);
#pragma unroll
    for (int dt = 0; dt < 4; ++dt) {
      const int d = dt * 32 + l31, swz = (d & 7) << 3;
      const bf16* vbp = &ldsV[buf][d * 64];
#pragma unroll
      for (int ksl = 0; ksl < 4; ++ksl) {
        bf16x8 vfr = *(const bf16x8*)&vbp[(ksl * 16 + 8 * hi) ^ swz];
        o[dt] = MFMA32(vfr, pa[ksl], o[dt]);
      }
    }
    __builtin_amdgcn_s_setprio(0);
  };

  // ---- main loop: 9 phases; A computes tile ph, B computes tile ph-1 ----
  issue(0);
  stage(0);
  issue(1);
  lgkm_barrier();
#pragma unroll 1
  for (int ph = 0; ph < 9; ++ph) {
    if (ph + 1 < 8) {
      stage((ph + 1) % 3);               // consumes regs issued at ph-1
      if (ph + 2 < 8) issue(ph + 2);     // in flight across the barrier
    }
    if (grpA) {
      if (ph < need) compute(ph % 3, ph + 1 == need);
    } else {
      const int kt = ph - 1;
      if (kt >= 0 && kt < need) compute(kt % 3, kt + 1 == need);
    }
    if (ph + 1 < 9) lgkm_barrier();
  }

  // ---- epilogue: combine partner l, divide, store O^T regs ----
  l += __shfl_xor(l, 32, 64);
  const float inv = 1.f / l;
  float* op = Og + ((size_t)(b * kS + qg) * kHq + hq) * kD;
#pragma unroll
  for (int dt = 0; dt < 4; ++dt)
#pragma unroll
    for (int rq = 0; rq < 4; ++rq) {
      f32x4 st;
#pragma unroll
      for (int rr = 0; rr < 4; ++rr) st[rr] = o[dt][4 * rq + rr] * inv;
      *(f32x4*)(op + dt * 32 + 8 * rq + 4 * hi) = st;
    }
}

extern "C" void kernel_launch(void* const* d_in, const int* in_sizes, int n_in,
                              void* d_out, int out_size, void* d_ws, size_t ws_size,
                              hipStream_t stream) {
  (void)in_sizes; (void)n_in; (void)d_ws; (void)ws_size; (void)out_size;
  const float* Q = (const float*)d_in[0];
  const float* K = (const float*)d_in[1];
  const float* V = (const float*)d_in[2];
  float* O = (float*)d_out;
  dim3 grid(256);   // (b2, n4, hq16, p2), XCD-grouped; 1 block/CU
  dim3 block(512);  // 8 waves x 32 q-rows, A/B staggered
  hipLaunchKernelGGL(attn_chunk, grid, block, 0, stream, Q, K, V, O);
}